// Round 6
// baseline (263.928 us; speedup 1.0000x reference)
//
#include <hip/hip_runtime.h>
#include <cstdint>

#define ALPHA 0.2f

constexpr int NB = 8;
constexpr int NN = 2048;
constexpr int NF = 256;

typedef __attribute__((ext_vector_type(8))) short bf16x8;
typedef __attribute__((ext_vector_type(4))) float f32x4;

__device__ __forceinline__ float bf2f(unsigned short u) {
    union { unsigned int i; float f; } v;
    v.i = ((unsigned int)u) << 16;
    return v.f;
}
__device__ __forceinline__ unsigned short f2bf(float f) {
    union { float f; unsigned int i; } v;
    v.f = f;
    v.i += 0x7fffu + ((v.i >> 16) & 1);  // round-to-nearest-even
    return (unsigned short)(v.i >> 16);
}

// ---------------------------------------------------------------------------
// Kernel 0: WT[f][k] = bf16(W[k][f]) transpose+cast; also zero s1/s2
// ---------------------------------------------------------------------------
__global__ __launch_bounds__(256) void k_wt(const float* __restrict__ W,
                                            unsigned short* __restrict__ WT,
                                            float* __restrict__ s1,
                                            float* __restrict__ s2) {
    const int t = threadIdx.x;
    const int gid = blockIdx.x * 256 + t;
    s1[gid] = 0.f;
    s2[gid] = 0.f;
    const int k = blockIdx.x * 4 + (t >> 6);
    const int f0 = (t & 63) * 4;
    const float4 w = *(const float4*)&W[k * NF + f0];
    WT[(f0 + 0) * NF + k] = f2bf(w.x);
    WT[(f0 + 1) * NF + k] = f2bf(w.y);
    WT[(f0 + 2) * NF + k] = f2bf(w.z);
    WT[(f0 + 3) * NF + k] = f2bf(w.w);
}

// ---------------------------------------------------------------------------
// Kernel 1: WhT = (h @ W)^T per batch, bf16 MFMA; fused s1/s2 epilogue.
// (unchanged — proven correct, ~6-8 us)
// ---------------------------------------------------------------------------
__global__ __launch_bounds__(256, 4) void k_wh(const float* __restrict__ h,
                                               const unsigned short* __restrict__ WT,
                                               const float* __restrict__ a,
                                               unsigned short* __restrict__ WhT,
                                               float* __restrict__ s1,
                                               float* __restrict__ s2) {
    __shared__ __align__(16) unsigned short As[64][72];  // [row][k] bf16
    __shared__ __align__(16) unsigned short Bs[64][72];  // [f][k]  bf16
    const int tid = threadIdx.x;
    const int lane = tid & 63;
    const int l16 = lane & 15;
    const int quad = lane >> 4;
    const int wave = tid >> 6;

    const int p = blockIdx.x;
    const int xcd = p & 7;
    const int q = p >> 3;                       // 0..127
    const int rowTile = xcd + (q >> 2) * 8;     // 0..255
    const int row0 = rowTile * 64;
    const int col0 = (q & 3) * 64;

    const int bb = row0 >> 11;
    const int n0 = row0 & (NN - 1);
    const int mb = (wave & 1) * 32;
    const int nb = (wave >> 1) * 32;

    f32x4 acc[2][2];
#pragma unroll
    for (int mf = 0; mf < 2; ++mf)
#pragma unroll
        for (int nf = 0; nf < 2; ++nf) acc[mf][nf] = (f32x4){0.f, 0.f, 0.f, 0.f};

    const int r0 = tid >> 4;          // 0..15  (+16 per group)
    const int k4 = (tid & 15) * 4;    // 0..60
    const int f0w = tid >> 3;         // 0..31  (+32 per group)
    const int k8 = (tid & 7) * 8;     // 0..56

    const float* hP = &h[(size_t)(row0 + r0) * NF + k4];
    const unsigned short* wP = &WT[(size_t)(col0 + f0w) * NF + k8];

    float4 h0, h1, h2, h3;
    uint4 wv0, wv1;

#define LOADW(K0)                                                      \
    do {                                                               \
        h0 = *(const float4*)&hP[(size_t)(0 * 16) * NF + (K0)];        \
        h1 = *(const float4*)&hP[(size_t)(1 * 16) * NF + (K0)];        \
        h2 = *(const float4*)&hP[(size_t)(2 * 16) * NF + (K0)];        \
        h3 = *(const float4*)&hP[(size_t)(3 * 16) * NF + (K0)];        \
        wv0 = *(const uint4*)&wP[(K0)];                                \
        wv1 = *(const uint4*)&wP[(size_t)32 * NF + (K0)];              \
    } while (0)

    LOADW(0);

    for (int k0 = 0; k0 < NF; k0 += 64) {
        ushort4 o;
        o.x = f2bf(h0.x); o.y = f2bf(h0.y); o.z = f2bf(h0.z); o.w = f2bf(h0.w);
        *(ushort4*)&As[r0 + 0][k4] = o;
        o.x = f2bf(h1.x); o.y = f2bf(h1.y); o.z = f2bf(h1.z); o.w = f2bf(h1.w);
        *(ushort4*)&As[r0 + 16][k4] = o;
        o.x = f2bf(h2.x); o.y = f2bf(h2.y); o.z = f2bf(h2.z); o.w = f2bf(h2.w);
        *(ushort4*)&As[r0 + 32][k4] = o;
        o.x = f2bf(h3.x); o.y = f2bf(h3.y); o.z = f2bf(h3.z); o.w = f2bf(h3.w);
        *(ushort4*)&As[r0 + 48][k4] = o;
        *(uint4*)&Bs[f0w][k8] = wv0;
        *(uint4*)&Bs[f0w + 32][k8] = wv1;
        __syncthreads();
        if (k0 + 64 < NF) LOADW(k0 + 64);
#pragma unroll
        for (int ks = 0; ks < 64; ks += 32) {
            bf16x8 av[2], bv[2];
#pragma unroll
            for (int mf = 0; mf < 2; ++mf)
                av[mf] = *(const bf16x8*)&As[mb + mf * 16 + l16][ks + quad * 8];
#pragma unroll
            for (int nf = 0; nf < 2; ++nf)
                bv[nf] = *(const bf16x8*)&Bs[nb + nf * 16 + l16][ks + quad * 8];
#pragma unroll
            for (int mf = 0; mf < 2; ++mf)
#pragma unroll
                for (int nf = 0; nf < 2; ++nf)
                    acc[mf][nf] = __builtin_amdgcn_mfma_f32_16x16x32_bf16(
                        av[mf], bv[nf], acc[mf][nf], 0, 0, 0);
        }
        __syncthreads();
    }
#undef LOADW

#pragma unroll
    for (int mf = 0; mf < 2; ++mf) {
#pragma unroll
        for (int nf = 0; nf < 2; ++nf) {
            const size_t f = col0 + nb + nf * 16 + l16;
            const int nr = n0 + mb + mf * 16 + quad * 4;
            ushort4 o;
            o.x = f2bf(acc[mf][nf][0]);
            o.y = f2bf(acc[mf][nf][1]);
            o.z = f2bf(acc[mf][nf][2]);
            o.w = f2bf(acc[mf][nf][3]);
            *(ushort4*)&WhT[((size_t)bb * NF + f) * NN + nr] = o;
        }
    }

    float a1v[2], a2v[2];
#pragma unroll
    for (int nf = 0; nf < 2; ++nf) {
        const int f = col0 + nb + nf * 16 + l16;
        a1v[nf] = a[f];
        a2v[nf] = a[NF + f];
    }
#pragma unroll
    for (int mf = 0; mf < 2; ++mf) {
#pragma unroll
        for (int r = 0; r < 4; ++r) {
            float p1 = acc[mf][0][r] * a1v[0] + acc[mf][1][r] * a1v[1];
            float p2 = acc[mf][0][r] * a2v[0] + acc[mf][1][r] * a2v[1];
            p1 += __shfl_xor(p1, 1); p2 += __shfl_xor(p2, 1);
            p1 += __shfl_xor(p1, 2); p2 += __shfl_xor(p2, 2);
            p1 += __shfl_xor(p1, 4); p2 += __shfl_xor(p2, 4);
            p1 += __shfl_xor(p1, 8); p2 += __shfl_xor(p2, 8);
            if (l16 == 0) {
                const int n = n0 + mb + mf * 16 + quad * 4 + r;
                atomicAdd(&s1[bb * NN + n], p1);
                atomicAdd(&s2[bb * NN + n], p2);
            }
        }
    }
}

// ---------------------------------------------------------------------------
// Kernel 2: fused masked softmax + attn @ Wh.
// SAFE VERSION: round-2-proven ordering (single Pb buffer, two
// __syncthreads per iteration) + the structural wins kept from the rework:
//  * NO WhsT LDS staging: B-fragments (16 contiguous bytes of WhT[b][f][j])
//    load directly from global (L2-resident, one batch per XCD).
//  * QBLK=32, f-split x2: grid 1024 = 8 b x 64 q-tiles x 2 f-halves,
//    256 thr, LDS ~4.9 KB, 4 blocks/CU (16 waves/CU) for latency hiding.
//  * Register prefetch of next tile's adj/s2 issued between the barriers.
// ---------------------------------------------------------------------------
__global__ __launch_bounds__(256, 4) void k_attn(const unsigned short* __restrict__ WhT,
                                                 const int* __restrict__ adj,
                                                 const float* __restrict__ s1g,
                                                 const float* __restrict__ s2g,
                                                 float* __restrict__ out) {
    __shared__ __align__(16) unsigned short Pb[32][72];  // [i][j] bf16
    __shared__ float s1_s[32];
    __shared__ float l_s[32];

    const int tid = threadIdx.x;
    const int lane = tid & 63;
    const int l16 = lane & 15;
    const int quad = lane >> 4;
    const int wave = tid >> 6;                  // 0..3
    const int bb = blockIdx.x & 7;              // one batch per XCD
    const int rest = blockIdx.x >> 3;           // 0..127
    const int i0 = (rest >> 1) * 32;            // q-tile base 0..2016
    const int fbase = (rest & 1) * 128 + wave * 32;  // this wave's 32-f slice

    if (tid < 32) {
        s1_s[tid] = s1g[bb * NN + i0 + tid];
        l_s[tid] = 0.f;
    }
    __syncthreads();

    f32x4 acc[2][2];
#pragma unroll
    for (int m = 0; m < 2; ++m)
#pragma unroll
        for (int nf = 0; nf < 2; ++nf) acc[m][nf] = (f32x4){0.f, 0.f, 0.f, 0.f};

    const size_t whtBase = (size_t)bb * NF * NN;
    const size_t adjBase = (size_t)bb * NN * NN;

    // P-compute geometry: thread (pIr, pKq) covers rows {pIr, pIr+16}, 4 j's
    const int pIr = tid >> 4;            // 0..15
    const int pKq = (tid & 15) * 4;      // 0..60
    const int* adjP0 = &adj[adjBase + (size_t)(i0 + pIr) * NN + pKq];
    const int* adjP1 = adjP0 + 16 * NN;
    const float* s2P = &s2g[bb * NN + pKq];

    // B-fragment base pointers (nf=0 / nf=1 rows); k0 handled by +32 offset
    const unsigned short* whB0 = &WhT[whtBase + (size_t)(fbase + l16) * NN + quad * 8];
    const unsigned short* whB1 = whB0 + (size_t)16 * NN;

    int4 am0, am1;
    float4 sv0;
    am0 = *(const int4*)&adjP0[0];
    am1 = *(const int4*)&adjP1[0];
    sv0 = *(const float4*)&s2P[0];

    for (int t = 0; t < NN / 64; ++t) {
        const int j0 = t * 64;
        // ---- P compute (uses prefetched am/sv) -> Pb ----
#pragma unroll
        for (int it = 0; it < 2; ++it) {
            const int ir = pIr + it * 16;
            const int4 av = it ? am1 : am0;
            const float s1v = s1_s[ir];
            float x0 = s1v + sv0.x, x1 = s1v + sv0.y;
            float x2 = s1v + sv0.z, x3 = s1v + sv0.w;
            x0 = x0 > 0.f ? x0 : ALPHA * x0;
            x1 = x1 > 0.f ? x1 : ALPHA * x1;
            x2 = x2 > 0.f ? x2 : ALPHA * x2;
            x3 = x3 > 0.f ? x3 : ALPHA * x3;
            const float p0 = av.x > 0 ? __expf(x0) : 0.f;
            const float p1 = av.y > 0 ? __expf(x1) : 0.f;
            const float p2 = av.z > 0 ? __expf(x2) : 0.f;
            const float p3 = av.w > 0 ? __expf(x3) : 0.f;
            uint2 pk;
            pk.x = (unsigned int)f2bf(p0) | ((unsigned int)f2bf(p1) << 16);
            pk.y = (unsigned int)f2bf(p2) | ((unsigned int)f2bf(p3) << 16);
            *(uint2*)&Pb[ir][pKq] = pk;
            float ps = (p0 + p1) + (p2 + p3);
            ps += __shfl_xor(ps, 8);
            ps += __shfl_xor(ps, 4);
            ps += __shfl_xor(ps, 2);
            ps += __shfl_xor(ps, 1);
            if ((tid & 15) == 0) l_s[ir] += ps;  // unique thread per ir
        }
        // ---- B loads for THIS tile (complete by first barrier's drain) ----
        const uint4 b00 = *(const uint4*)&whB0[j0];
        const uint4 b01 = *(const uint4*)&whB0[j0 + 32];
        const uint4 b10 = *(const uint4*)&whB1[j0];
        const uint4 b11 = *(const uint4*)&whB1[j0 + 32];
        // ---- publish Pb ----
        __syncthreads();
        // ---- adj/s2 prefetch for NEXT tile (flies during MFMA) ----
        if (t + 1 < NN / 64) {
            am0 = *(const int4*)&adjP0[j0 + 64];
            am1 = *(const int4*)&adjP1[j0 + 64];
            sv0 = *(const float4*)&s2P[j0 + 64];
        }
        // ---- MFMA: out[32 x 32f per wave] += P[32 x 64j] * Wh ----
        {
            bf16x8 a0 = *(const bf16x8*)&Pb[l16][quad * 8];
            bf16x8 a1 = *(const bf16x8*)&Pb[16 + l16][quad * 8];
            acc[0][0] = __builtin_amdgcn_mfma_f32_16x16x32_bf16(
                a0, *(const bf16x8*)&b00, acc[0][0], 0, 0, 0);
            acc[1][0] = __builtin_amdgcn_mfma_f32_16x16x32_bf16(
                a1, *(const bf16x8*)&b00, acc[1][0], 0, 0, 0);
            acc[0][1] = __builtin_amdgcn_mfma_f32_16x16x32_bf16(
                a0, *(const bf16x8*)&b10, acc[0][1], 0, 0, 0);
            acc[1][1] = __builtin_amdgcn_mfma_f32_16x16x32_bf16(
                a1, *(const bf16x8*)&b10, acc[1][1], 0, 0, 0);
            a0 = *(const bf16x8*)&Pb[l16][32 + quad * 8];
            a1 = *(const bf16x8*)&Pb[16 + l16][32 + quad * 8];
            acc[0][0] = __builtin_amdgcn_mfma_f32_16x16x32_bf16(
                a0, *(const bf16x8*)&b01, acc[0][0], 0, 0, 0);
            acc[1][0] = __builtin_amdgcn_mfma_f32_16x16x32_bf16(
                a1, *(const bf16x8*)&b01, acc[1][0], 0, 0, 0);
            acc[0][1] = __builtin_amdgcn_mfma_f32_16x16x32_bf16(
                a0, *(const bf16x8*)&b11, acc[0][1], 0, 0, 0);
            acc[1][1] = __builtin_amdgcn_mfma_f32_16x16x32_bf16(
                a1, *(const bf16x8*)&b11, acc[1][1], 0, 0, 0);
        }
        // ---- read-done barrier: safe to rewrite Pb next iteration ----
        __syncthreads();
    }

    // ---- epilogue ----
    if (tid < 32) l_s[tid] = 1.0f / l_s[tid];
    __syncthreads();

#pragma unroll
    for (int m = 0; m < 2; ++m) {
#pragma unroll
        for (int r = 0; r < 4; ++r) {
            const int row = m * 16 + quad * 4 + r;
            const float inv = l_s[row];
#pragma unroll
            for (int nf = 0; nf < 2; ++nf) {
                out[((size_t)bb * NN + i0 + row) * NF + fbase + nf * 16 + l16] =
                    acc[m][nf][r] * inv;
            }
        }
    }
}

// ---------------------------------------------------------------------------
extern "C" void kernel_launch(void* const* d_in, const int* in_sizes, int n_in,
                              void* d_out, int out_size, void* d_ws, size_t ws_size,
                              hipStream_t stream) {
    const float* h = (const float*)d_in[0];
    const int* adj = (const int*)d_in[1];
    const float* W = (const float*)d_in[2];
    const float* a = (const float*)d_in[3];
    float* out = (float*)d_out;

    unsigned short* WhT = (unsigned short*)d_ws;  // 8.4 MB bf16, [b][f][n]
    float* s1 = (float*)((char*)d_ws + (size_t)NB * NN * NF * sizeof(unsigned short));
    float* s2 = s1 + (size_t)NB * NN;
    unsigned short* WT = (unsigned short*)(s2 + (size_t)NB * NN);  // 128 KB

    k_wt<<<dim3(64), dim3(256), 0, stream>>>(W, WT, s1, s2);
    k_wh<<<dim3((NB * NN / 64) * (NF / 64)), dim3(256), 0, stream>>>(h, WT, a, WhT, s1, s2);
    // grid = NB batches x (NN/32) q-tiles x 2 f-halves = 1024 blocks
    k_attn<<<dim3(NB * (NN / 32) * 2), dim3(256), 0, stream>>>(WhT, adj, s1, s2, out);
}